// Round 1
// baseline (561.459 us; speedup 1.0000x reference)
//
#include <hip/hip_runtime.h>
#include <math.h>

// Problem constants (match reference)
#define NTGT 256
#define NB 16
#define NH 256
#define NW 256
#define GSIZE (NB * NH * NW)   // 1,048,576

// acc layout in d_ws (first 32 floats):
//  u32 view: [0..1] n_obj[c], [2..3] n_cleared[c]
//  f32:      [4..5]  s_conf_obj
//            [6..7]  s_x
//            [8..9]  s_y
//            [10..11] s_w
//            [12..13] s_h
//            [14..15] s_angle
//            [16..17] s_ring
//            [18..19] s_cleared_softplus
//            [20..21] s_all_softplus

__device__ __forceinline__ float softplusf(float z) {
    // logaddexp(z, 0) = max(z,0) + log1p(exp(-|z|))
    return fmaxf(z, 0.0f) + log1pf(expf(-fabsf(z)));
}
__device__ __forceinline__ float sigmoidf(float t) {
    return 1.0f / (1.0f + expf(-t));
}

__global__ void init_acc(float* acc) {
    if (threadIdx.x < 32) acc[threadIdx.x] = 0.0f;
}

// One thread per (target, window-entry): 256 targets * 36 entries = 9216 threads.
// Determines for its cell (per class): winner-candidate (min (vflat, e) among
// valid entries at cell) and cleared-owner (min e among valid entries at cell),
// then computes heat/cold for candidates only and accumulates loss terms.
__global__ __launch_bounds__(64) void entry_kernel(const float* __restrict__ predict,
                                                   const float* __restrict__ targets,
                                                   float* acc) {
#pragma clang fp contract(off)
    __shared__ float tg[NTGT * 7];
    for (int i = threadIdx.x; i < NTGT * 7; i += 64) tg[i] = targets[i];
    __syncthreads();

    const int e = blockIdx.x * 64 + threadIdx.x;   // 0..9215 (144*64 exactly)
    const int n = e / 36;
    const int sub = e - n * 36;
    const int kj = sub / 6;        // J-axis offset (first K dim in reference)
    const int ki = sub - kj * 6;   // I-axis offset (second K dim)

    const float* T = &tg[n * 7];
    const int b   = (int)T[0];
    const int cls = (int)T[1];
    const float cx = T[2] * 0.125f, cy = T[3] * 0.125f;
    const float bw = T[4] * 0.125f, bh = T[5] * 0.125f;
    const float ang = T[6];

    const int i0 = (int)floorf(cx - 2.0f);
    const int j0 = (int)floorf(cy - 2.0f);
    const int I = i0 + ki, J = j0 + kj;
    const float ox = cx - (float)I;
    const float oy = cy - (float)J;

    // validf = inb & off  (lower=-2, upper=3)
    if (!(I >= 0 && I < NW && J >= 0 && J < NH)) return;
    if (!(ox >= -2.0f && ox <= 3.0f && oy >= -2.0f && oy <= 3.0f)) return;

    const float vfl = fminf(fabsf(ox - 0.5f), fabsf(oy - 0.5f));
    const unsigned long long mypack =
        ((unsigned long long)__float_as_uint(vfl) << 32) | (unsigned)e;
    unsigned long long best = mypack;   // min over (vflat, index) at this cell
    int ownmin = e;                     // min index among valid entries at cell

    // Scan other targets: same batch+class whose 6x6 window covers (I,J).
    for (int m = 0; m < NTGT; ++m) {
        if (m == n) continue;
        const float* Tm = &tg[m * 7];
        if ((int)Tm[0] != b || (int)Tm[1] != cls) continue;
        const float mcx = Tm[2] * 0.125f, mcy = Tm[3] * 0.125f;
        const int mi0 = (int)floorf(mcx - 2.0f);
        const int mj0 = (int)floorf(mcy - 2.0f);
        const int kip = I - mi0, kjp = J - mj0;
        if (kip < 0 || kip > 5 || kjp < 0 || kjp > 5) continue;
        const float oxp = mcx - (float)I;
        const float oyp = mcy - (float)J;
        // inb is a cell property (shared); only need 'off' for validf'
        if (!(oxp >= -2.0f && oxp <= 3.0f && oyp >= -2.0f && oyp <= 3.0f)) continue;
        const int ep = (m * 6 + kjp) * 6 + kip;
        ownmin = min(ownmin, ep);
        const float vflp = fminf(fabsf(oxp - 0.5f), fabsf(oyp - 0.5f));
        const unsigned long long pk =
            ((unsigned long long)__float_as_uint(vflp) << 32) | (unsigned)ep;
        if (pk < best) best = pk;
    }

    const bool isOwner = (ownmin == e);
    const bool isWinC  = (best == mypack);
    if (!isOwner && !isWinC) return;

    // heat / inexp at cell (I,J) for (b, cls): loop all matching targets.
    const float gx = (float)I + 0.5f;
    const float gy = (float)J + 0.5f;
    bool heat = false, anyexp = false;
    for (int m = 0; m < NTGT; ++m) {
        const float* Tm = &tg[m * 7];
        if ((int)Tm[0] != b || (int)Tm[1] != cls) continue;
        const float mcx = Tm[2] * 0.125f, mcy = Tm[3] * 0.125f;
        const float mbw = Tm[4] * 0.125f, mbh = Tm[5] * 0.125f;
        float sa, ca;
        sincosf(Tm[6], &sa, &ca);
        const float vx =  gx * ca + gy * sa;
        const float vy = -gx * sa + gy * ca;
        const float bx =  mcx * ca + mcy * sa;
        const float by = -mcx * sa + mcy * ca;
        const float x3 = bx - 0.5f * mbh, x4 = bx + 0.5f * mbh;
        const float y3 = by - 0.5f * mbw, y4 = by + 0.5f * mbw;
        heat   |= (vx >= x3 && vx <= x4 && vy >= y3 && vy <= y4);
        anyexp |= (vx >= x3 - 0.5f && vx <= x4 + 0.5f &&
                   vy >= y3 - 0.5f && vy <= y4 + 0.5f);
    }

    unsigned* cnt = (unsigned*)acc;
    const size_t base = (size_t)b * 8 * 65536 + (size_t)J * 256 + (size_t)I;

    // cleared = validf & ~cold = validf & anyexp; count each cell once (owner)
    if (isOwner && anyexp) {
        const float z = predict[base + (size_t)(6 + cls) * 65536];
        atomicAdd(&acc[18 + cls], softplusf(z));
        atomicAdd(&cnt[2 + cls], 1u);
    }

    // winner = elig (validf & heat) & min (vflat, idx) at cell
    if (isWinC && heat) {
        const float p0 = predict[base];
        const float p1 = predict[base + 65536];
        const float p2 = predict[base + 2 * 65536];
        const float p3 = predict[base + 3 * 65536];
        const float p4 = predict[base + 4 * 65536];
        const float p5 = predict[base + 5 * 65536];
        const float z  = predict[base + (size_t)(6 + cls) * 65536];
        const float xs = sigmoidf(p0) * 5.0f - 2.0f;
        const float ys = sigmoidf(p1) * 5.0f - 2.0f;
        const float pp = sigmoidf(p4) * 2.0f - 1.0f;
        const float qq = sigmoidf(p5) * 2.0f - 1.0f;
        const float tw = logf(bw), th = logf(bh);
        const float wt = th - tw, awt = fabsf(wt);
        float s2a, c2a;
        sincosf(2.0f * ang, &s2a, &c2a);
        atomicAdd(&acc[4 + cls],  softplusf(-z));
        atomicAdd(&acc[6 + cls],  (xs - ox) * (xs - ox));
        atomicAdd(&acc[8 + cls],  (ys - oy) * (ys - oy));
        atomicAdd(&acc[10 + cls], (p2 - tw) * (p2 - tw));
        atomicAdd(&acc[12 + cls], (p3 - th) * (p3 - th));
        atomicAdd(&acc[14 + cls], awt * (fabsf(pp - c2a) + fabsf(qq - s2a)));
        atomicAdd(&acc[16 + cls], awt * fabsf(pp * pp + qq * qq - 1.0f));
        atomicAdd(&cnt[cls], 1u);
    }
}

// Full-grid softplus sum over channels 6 and 7 (per class).
// 16 batches * 2 planes * 65536 floats = 2,097,152 floats = 524,288 float4s.
__global__ __launch_bounds__(256) void conf_sum(const float* __restrict__ predict,
                                                float* acc) {
    const int idx = blockIdx.x * 256 + threadIdx.x;   // 0..524287
    const int b   = idx >> 15;                        // 32768 float4 per batch
    const int r   = idx & 32767;
    const int ch  = 6 + (r >> 14);                    // 16384 float4 per plane
    const int pos = r & 16383;
    const float4* pl =
        reinterpret_cast<const float4*>(predict + (size_t)(b * 8 + ch) * 65536);
    const float4 v = pl[pos];
    float s = softplusf(v.x) + softplusf(v.y) + softplusf(v.z) + softplusf(v.w);
    // 16384 % 64 == 0 → each 64-lane wave has a uniform class
    for (int o = 32; o > 0; o >>= 1) s += __shfl_down(s, o, 64);
    if ((threadIdx.x & 63) == 0) atomicAdd(&acc[20 + (ch - 6)], s);
}

__global__ void final_kernel(const float* __restrict__ acc, float* __restrict__ out) {
    const unsigned* cnt = (const unsigned*)acc;
    float total = 0.0f;
    for (int c = 0; c < 2; ++c) {
        const unsigned nobj = cnt[c];
        if (nobj > 0) {
            const float dn = (float)nobj;
            // n_no = SIZE - |cleared ∪ obj| = SIZE - n_cleared  (obj ⊆ cleared)
            const float dno = fmaxf((float)(GSIZE - (int)cnt[2 + c]), 1.0f);
            const float loss =
                acc[4 + c] / dn                          // conf_obj
                + (acc[20 + c] - acc[18 + c]) / dno      // NO_OBJ_SCALE * conf_noobj
                + (acc[6 + c] + acc[8 + c] + acc[10 + c] + acc[12 + c]
                   + acc[14 + c] + acc[16 + c]) / dn;    // x,y,w,h,angle,ring
            total += loss;
        }
    }
    out[0] = total;
}

extern "C" void kernel_launch(void* const* d_in, const int* in_sizes, int n_in,
                              void* d_out, int out_size, void* d_ws, size_t ws_size,
                              hipStream_t stream) {
    const float* predict = (const float*)d_in[0];
    const float* targets = (const float*)d_in[1];
    float* out = (float*)d_out;
    float* acc = (float*)d_ws;   // needs only 128 bytes of scratch

    init_acc<<<1, 64, 0, stream>>>(acc);
    entry_kernel<<<144, 64, 0, stream>>>(predict, targets, acc);
    conf_sum<<<2048, 256, 0, stream>>>(predict, acc);
    final_kernel<<<1, 1, 0, stream>>>(acc, out);
}

// Round 2
// 422.148 us; speedup vs baseline: 1.3300x; 1.3300x over previous
//
#include <hip/hip_runtime.h>
#include <math.h>

// Problem constants (match reference)
#define NTGT 256
#define NB 16
#define NH 256
#define NW 256
#define GSIZE (NB * NH * NW)   // 1,048,576

// ---- d_ws layout (float/int units of 4 bytes) ----
// [0..31]   acc:  u32 [0..1] n_obj[c], [2..3] n_cleared[c]
//           f32 [4..5] s_conf_obj, [6..7] s_x, [8..9] s_y, [10..11] s_w,
//               [12..13] s_h, [14..15] s_angle, [16..17] s_ring,
//               [18..19] s_cleared_softplus
#define TP_I0   32      // int[256]
#define TP_J0   288     // int[256]
#define TP_CX   544     // float[256]
#define TP_CY   800
#define TP_CA   1056
#define TP_SA   1312
#define TP_X3   1568
#define TP_X4   1824
#define TP_Y3   2080
#define TP_Y4   2336
#define TP_G    2592    // int[256] group = b*2+cls
#define GLIST   2848    // int[256] target ids sorted by group
#define GSTART  3104    // int[33]  CSR offsets
#define PART    3168    // float[256] conf_sum partials

__device__ __forceinline__ float softplusf(float z) {
    return fmaxf(z, 0.0f) + log1pf(expf(-fabsf(z)));
}
__device__ __forceinline__ float sigmoidf(float t) {
    return 1.0f / (1.0f + expf(-t));
}

// One block, one thread per target: derive everything that the O(entries*group)
// loops need, and counting-sort targets into per-(batch,class) CSR lists.
__global__ __launch_bounds__(256) void precompute(const float* __restrict__ targets,
                                                  float* __restrict__ ws) {
#pragma clang fp contract(off)
    __shared__ int cnt[32];
    __shared__ int offs[33];
    const int t = threadIdx.x;
    if (t < 32) { cnt[t] = 0; ws[t] = 0.0f; }   // zero group counts + acc
    __syncthreads();

    const float* T = targets + t * 7;
    const int b   = (int)T[0];
    const int cls = (int)T[1];
    const float cx = T[2] * 0.125f, cy = T[3] * 0.125f;
    const float bw = T[4] * 0.125f, bh = T[5] * 0.125f;
    float sa, ca;
    sincosf(T[6], &sa, &ca);
    const float bx =  cx * ca + cy * sa;
    const float by = -cx * sa + cy * ca;
    const int g = b * 2 + cls;

    const int pos = atomicAdd(&cnt[g], 1);
    __syncthreads();
    if (t == 0) {
        int s = 0;
        for (int i = 0; i < 32; ++i) { offs[i] = s; s += cnt[i]; }
        offs[32] = s;
    }
    __syncthreads();

    int* iws = (int*)ws;
    iws[GLIST + offs[g] + pos] = t;
    if (t < 33) iws[GSTART + t] = offs[t];

    iws[TP_I0 + t] = (int)floorf(cx - 2.0f);
    iws[TP_J0 + t] = (int)floorf(cy - 2.0f);
    ws[TP_CX + t] = cx;  ws[TP_CY + t] = cy;
    ws[TP_CA + t] = ca;  ws[TP_SA + t] = sa;
    ws[TP_X3 + t] = bx - bh * 0.5f;  ws[TP_X4 + t] = bx + bh * 0.5f;
    ws[TP_Y3 + t] = by - bw * 0.5f;  ws[TP_Y4 + t] = by + bw * 0.5f;
    iws[TP_G + t] = g;
}

// One thread per (target, window-entry): 256*36 = 9216 = 36 blocks * 256.
__global__ __launch_bounds__(256) void entry_kernel(const float* __restrict__ predict,
                                                    const float* __restrict__ targets,
                                                    float* __restrict__ ws) {
#pragma clang fp contract(off)
    __shared__ float s_cx[NTGT], s_cy[NTGT], s_ca[NTGT], s_sa[NTGT];
    __shared__ float s_x3[NTGT], s_x4[NTGT], s_y3[NTGT], s_y4[NTGT];
    __shared__ int   s_i0[NTGT], s_j0[NTGT], s_g[NTGT], s_gl[NTGT];
    __shared__ int   s_gs[33];

    const int t = threadIdx.x;
    const int* iws = (const int*)ws;
    s_cx[t] = ws[TP_CX + t];  s_cy[t] = ws[TP_CY + t];
    s_ca[t] = ws[TP_CA + t];  s_sa[t] = ws[TP_SA + t];
    s_x3[t] = ws[TP_X3 + t];  s_x4[t] = ws[TP_X4 + t];
    s_y3[t] = ws[TP_Y3 + t];  s_y4[t] = ws[TP_Y4 + t];
    s_i0[t] = iws[TP_I0 + t]; s_j0[t] = iws[TP_J0 + t];
    s_g[t]  = iws[TP_G + t];  s_gl[t] = iws[GLIST + t];
    if (t < 33) s_gs[t] = iws[GSTART + t];
    __syncthreads();

    const int e = blockIdx.x * 256 + t;     // 0..9215
    const int n = e / 36;
    const int sub = e - n * 36;
    const int kj = sub / 6;
    const int ki = sub - kj * 6;

    const int g = s_g[n];
    const int I = s_i0[n] + ki, J = s_j0[n] + kj;
    const float cx = s_cx[n], cy = s_cy[n];
    const float ox = cx - (float)I;
    const float oy = cy - (float)J;

    if (!(I >= 0 && I < NW && J >= 0 && J < NH)) return;
    if (!(ox >= -2.0f && ox <= 3.0f && oy >= -2.0f && oy <= 3.0f)) return;

    const float vfl = fminf(fabsf(ox - 0.5f), fabsf(oy - 0.5f));
    const unsigned long long mypack =
        ((unsigned long long)__float_as_uint(vfl) << 32) | (unsigned)e;
    unsigned long long best = mypack;
    int ownmin = e;

    const int gs = s_gs[g], ge = s_gs[g + 1];
    for (int p = gs; p < ge; ++p) {
        const int m = s_gl[p];
        if (m == n) continue;
        const int kip = I - s_i0[m];
        if (kip < 0 || kip > 5) continue;
        const int kjp = J - s_j0[m];
        if (kjp < 0 || kjp > 5) continue;
        const float oxp = s_cx[m] - (float)I;
        const float oyp = s_cy[m] - (float)J;
        if (!(oxp >= -2.0f && oxp <= 3.0f && oyp >= -2.0f && oyp <= 3.0f)) continue;
        const int ep = (m * 6 + kjp) * 6 + kip;
        ownmin = min(ownmin, ep);
        const float vflp = fminf(fabsf(oxp - 0.5f), fabsf(oyp - 0.5f));
        const unsigned long long pk =
            ((unsigned long long)__float_as_uint(vflp) << 32) | (unsigned)ep;
        if (pk < best) best = pk;
    }

    const bool isOwner = (ownmin == e);
    const bool isWinC  = (best == mypack);
    if (!isOwner && !isWinC) return;

    // heat / inexp at cell (I,J) over this (b,cls) group only.
    const float gx = (float)I + 0.5f;
    const float gy = (float)J + 0.5f;
    bool heat = false, anyexp = false;
    for (int p = gs; p < ge; ++p) {
        const int m = s_gl[p];
        const float ca = s_ca[m], sa = s_sa[m];
        const float vx =  gx * ca + gy * sa;
        const float vy = -gx * sa + gy * ca;
        const float x3 = s_x3[m], x4 = s_x4[m];
        const float y3 = s_y3[m], y4 = s_y4[m];
        heat   |= (vx >= x3 && vx <= x4 && vy >= y3 && vy <= y4);
        anyexp |= (vx >= x3 - 0.5f && vx <= x4 + 0.5f &&
                   vy >= y3 - 0.5f && vy <= y4 + 0.5f);
    }

    unsigned* cnt = (unsigned*)ws;
    const int b = g >> 1, cls = g & 1;
    const size_t base = (size_t)b * 8 * 65536 + (size_t)J * 256 + (size_t)I;

    if (isOwner && anyexp) {
        const float z = predict[base + (size_t)(6 + cls) * 65536];
        atomicAdd(&ws[18 + cls], softplusf(z));
        atomicAdd(&cnt[2 + cls], 1u);
    }

    if (isWinC && heat) {
        const float p0 = predict[base];
        const float p1 = predict[base + 65536];
        const float p2 = predict[base + 2 * 65536];
        const float p3 = predict[base + 3 * 65536];
        const float p4 = predict[base + 4 * 65536];
        const float p5 = predict[base + 5 * 65536];
        const float z  = predict[base + (size_t)(6 + cls) * 65536];
        const float bw = targets[n * 7 + 4] * 0.125f;
        const float bh = targets[n * 7 + 5] * 0.125f;
        const float ang = targets[n * 7 + 6];
        const float xs = sigmoidf(p0) * 5.0f - 2.0f;
        const float ys = sigmoidf(p1) * 5.0f - 2.0f;
        const float pp = sigmoidf(p4) * 2.0f - 1.0f;
        const float qq = sigmoidf(p5) * 2.0f - 1.0f;
        const float tw = logf(bw), th = logf(bh);
        const float wt = th - tw, awt = fabsf(wt);
        float s2a, c2a;
        sincosf(2.0f * ang, &s2a, &c2a);
        atomicAdd(&ws[4 + cls],  softplusf(-z));
        atomicAdd(&ws[6 + cls],  (xs - ox) * (xs - ox));
        atomicAdd(&ws[8 + cls],  (ys - oy) * (ys - oy));
        atomicAdd(&ws[10 + cls], (p2 - tw) * (p2 - tw));
        atomicAdd(&ws[12 + cls], (p3 - th) * (p3 - th));
        atomicAdd(&ws[14 + cls], awt * (fabsf(pp - c2a) + fabsf(qq - s2a)));
        atomicAdd(&ws[16 + cls], awt * fabsf(pp * pp + qq * qq - 1.0f));
        atomicAdd(&cnt[cls], 1u);
    }
}

// Full-grid softplus sum over channels 6,7. 524288 float4 total.
// 256 blocks x 256 threads, 8 float4/thread; one partial per block (no
// contended atomics). Class is uniform per block: (blockIdx.x>>6)&1.
__global__ __launch_bounds__(256) void conf_sum(const float* __restrict__ predict,
                                                float* __restrict__ ws) {
    __shared__ float red[4];
    const int t = threadIdx.x;
    const int j = blockIdx.x * 256 + t;      // 0..65535
    const int ch  = 6 + ((j >> 14) & 1);
    const int pos = j & 16383;
    const int bhi = j >> 15;
    float s = 0.0f;
    for (int it = 0; it < 8; ++it) {
        const int b = it * 2 + bhi;
        const float4 v = *reinterpret_cast<const float4*>(
            predict + (size_t)(b * 8 + ch) * 65536 + (size_t)pos * 4);
        s += softplusf(v.x) + softplusf(v.y) + softplusf(v.z) + softplusf(v.w);
    }
    for (int o = 32; o > 0; o >>= 1) s += __shfl_down(s, o, 64);
    if ((t & 63) == 0) red[t >> 6] = s;
    __syncthreads();
    if (t == 0) ws[PART + blockIdx.x] = red[0] + red[1] + red[2] + red[3];
}

__global__ __launch_bounds__(256) void final_kernel(const float* __restrict__ ws,
                                                    float* __restrict__ out) {
    __shared__ float r0[256], r1[256];
    const int t = threadIdx.x;
    const float v = ws[PART + t];
    const int c = (t >> 6) & 1;
    r0[t] = c ? 0.0f : v;
    r1[t] = c ? v : 0.0f;
    __syncthreads();
    for (int o = 128; o > 0; o >>= 1) {
        if (t < o) { r0[t] += r0[t + o]; r1[t] += r1[t + o]; }
        __syncthreads();
    }
    if (t == 0) {
        const unsigned* cnt = (const unsigned*)ws;
        const float sAll[2] = { r0[0], r1[0] };
        float total = 0.0f;
        for (int c2 = 0; c2 < 2; ++c2) {
            const unsigned nobj = cnt[c2];
            if (nobj > 0) {
                const float dn  = (float)nobj;
                const float dno = fmaxf((float)(GSIZE - (int)cnt[2 + c2]), 1.0f);
                total += ws[4 + c2] / dn
                       + (sAll[c2] - ws[18 + c2]) / dno
                       + (ws[6 + c2] + ws[8 + c2] + ws[10 + c2] + ws[12 + c2]
                          + ws[14 + c2] + ws[16 + c2]) / dn;
            }
        }
        out[0] = total;
    }
}

extern "C" void kernel_launch(void* const* d_in, const int* in_sizes, int n_in,
                              void* d_out, int out_size, void* d_ws, size_t ws_size,
                              hipStream_t stream) {
    const float* predict = (const float*)d_in[0];
    const float* targets = (const float*)d_in[1];
    float* out = (float*)d_out;
    float* ws = (float*)d_ws;     // ~14 KB used

    precompute<<<1, 256, 0, stream>>>(targets, ws);
    entry_kernel<<<36, 256, 0, stream>>>(predict, targets, ws);
    conf_sum<<<256, 256, 0, stream>>>(predict, ws);
    final_kernel<<<1, 256, 0, stream>>>(ws, out);
}

// Round 3
// 31.063 us; speedup vs baseline: 18.0750x; 13.5902x over previous
//
#include <hip/hip_runtime.h>
#include <math.h>

// Problem constants (match reference)
#define NTGT 256
#define NB 16
#define NH 256
#define NW 256
#define GSIZE (NB * NH * NW)   // 1,048,576

// ---- d_ws layout (float/int units of 4 bytes) ----
// [0..31]   acc:  u32 [0..1] n_obj[c], [2..3] n_cleared[c]
//           f32 [4..5] s_conf_obj, [6..7] s_x, [8..9] s_y, [10..11] s_w,
//               [12..13] s_h, [14..15] s_angle, [16..17] s_ring,
//               [18..19] s_cleared_softplus
#define TP_I0   32      // int[256]
#define TP_J0   288     // int[256]
#define TP_CX   544     // float[256]
#define TP_CY   800
#define TP_CA   1056
#define TP_SA   1312
#define TP_X3   1568
#define TP_X4   1824
#define TP_Y3   2080
#define TP_Y4   2336
#define TP_G    2592    // int[256] group = b*2+cls
#define GLIST   2848    // int[256] target ids sorted by group
#define GSTART  3104    // int[33]  CSR offsets
#define PART    3168    // float[256] conf_sum partials

__device__ __forceinline__ float softplusf(float z) {
    return fmaxf(z, 0.0f) + log1pf(expf(-fabsf(z)));
}
__device__ __forceinline__ float sigmoidf(float t) {
    return 1.0f / (1.0f + expf(-t));
}

// One block, one thread per target: derive everything the entry loops need,
// and counting-sort targets into per-(batch,class) CSR lists.
__global__ __launch_bounds__(256) void precompute(const float* __restrict__ targets,
                                                  float* __restrict__ ws) {
#pragma clang fp contract(off)
    __shared__ int cnt[32];
    __shared__ int offs[33];
    const int t = threadIdx.x;
    if (t < 32) { cnt[t] = 0; ws[t] = 0.0f; }   // zero group counts + acc
    __syncthreads();

    const float* T = targets + t * 7;
    const int b   = (int)T[0];
    const int cls = (int)T[1];
    const float cx = T[2] * 0.125f, cy = T[3] * 0.125f;
    const float bw = T[4] * 0.125f, bh = T[5] * 0.125f;
    float sa, ca;
    sincosf(T[6], &sa, &ca);
    const float bx =  cx * ca + cy * sa;
    const float by = -cx * sa + cy * ca;
    const int g = b * 2 + cls;

    const int pos = atomicAdd(&cnt[g], 1);
    __syncthreads();
    if (t == 0) {
        int s = 0;
        for (int i = 0; i < 32; ++i) { offs[i] = s; s += cnt[i]; }
        offs[32] = s;
    }
    __syncthreads();

    int* iws = (int*)ws;
    iws[GLIST + offs[g] + pos] = t;
    if (t < 33) iws[GSTART + t] = offs[t];

    iws[TP_I0 + t] = (int)floorf(cx - 2.0f);
    iws[TP_J0 + t] = (int)floorf(cy - 2.0f);
    ws[TP_CX + t] = cx;  ws[TP_CY + t] = cy;
    ws[TP_CA + t] = ca;  ws[TP_SA + t] = sa;
    ws[TP_X3 + t] = bx - bh * 0.5f;  ws[TP_X4 + t] = bx + bh * 0.5f;
    ws[TP_Y3 + t] = by - bw * 0.5f;  ws[TP_Y4 + t] = by + bw * 0.5f;
    iws[TP_G + t] = g;
}

// One thread per (target, window-entry): 256*36 = 9216 = 36 blocks * 256.
// All global accumulation is hierarchical: wave shuffle/ballot -> LDS -> one
// global atomic per block per slot (the R2 kernel's ~19k same-address global
// atomics WERE the 412 us).
__global__ __launch_bounds__(256) void entry_kernel(const float* __restrict__ predict,
                                                    const float* __restrict__ targets,
                                                    float* __restrict__ ws) {
#pragma clang fp contract(off)
    __shared__ float s_cx[NTGT], s_cy[NTGT], s_ca[NTGT], s_sa[NTGT];
    __shared__ float s_x3[NTGT], s_x4[NTGT], s_y3[NTGT], s_y4[NTGT];
    __shared__ int   s_i0[NTGT], s_j0[NTGT], s_g[NTGT], s_gl[NTGT];
    __shared__ int   s_gs[33];
    __shared__ float blksum[16];     // ws[4..19]
    __shared__ unsigned blkcnt[4];   // ws u32 [0..3]

    const int t = threadIdx.x;
    const int* iws = (const int*)ws;
    if (t < 16) blksum[t] = 0.0f;
    if (t >= 16 && t < 20) blkcnt[t - 16] = 0u;
    s_cx[t] = ws[TP_CX + t];  s_cy[t] = ws[TP_CY + t];
    s_ca[t] = ws[TP_CA + t];  s_sa[t] = ws[TP_SA + t];
    s_x3[t] = ws[TP_X3 + t];  s_x4[t] = ws[TP_X4 + t];
    s_y3[t] = ws[TP_Y3 + t];  s_y4[t] = ws[TP_Y4 + t];
    s_i0[t] = iws[TP_I0 + t]; s_j0[t] = iws[TP_J0 + t];
    s_g[t]  = iws[TP_G + t];  s_gl[t] = iws[GLIST + t];
    if (t < 33) s_gs[t] = iws[GSTART + t];
    __syncthreads();

    const int e = blockIdx.x * 256 + t;     // 0..9215
    const int n = e / 36;
    const int sub = e - n * 36;
    const int kj = sub / 6;
    const int ki = sub - kj * 6;

    const int g = s_g[n];
    const int cls = g & 1;
    const int b = g >> 1;
    const int I = s_i0[n] + ki, J = s_j0[n] + kj;
    const float cx = s_cx[n], cy = s_cy[n];
    const float ox = cx - (float)I;
    const float oy = cy - (float)J;

    const bool validf = (I >= 0 && I < NW && J >= 0 && J < NH) &&
                        (ox >= -2.0f && ox <= 3.0f && oy >= -2.0f && oy <= 3.0f);

    bool isOwner = false, isWinC = false;
    const int gs = s_gs[g], ge = s_gs[g + 1];
    if (validf) {
        const float vfl = fminf(fabsf(ox - 0.5f), fabsf(oy - 0.5f));
        const unsigned long long mypack =
            ((unsigned long long)__float_as_uint(vfl) << 32) | (unsigned)e;
        unsigned long long best = mypack;
        int ownmin = e;
        for (int p = gs; p < ge; ++p) {
            const int m = s_gl[p];
            if (m == n) continue;
            const int kip = I - s_i0[m];
            if (kip < 0 || kip > 5) continue;
            const int kjp = J - s_j0[m];
            if (kjp < 0 || kjp > 5) continue;
            const float oxp = s_cx[m] - (float)I;
            const float oyp = s_cy[m] - (float)J;
            if (!(oxp >= -2.0f && oxp <= 3.0f && oyp >= -2.0f && oyp <= 3.0f)) continue;
            const int ep = (m * 6 + kjp) * 6 + kip;
            ownmin = min(ownmin, ep);
            const float vflp = fminf(fabsf(oxp - 0.5f), fabsf(oyp - 0.5f));
            const unsigned long long pk =
                ((unsigned long long)__float_as_uint(vflp) << 32) | (unsigned)ep;
            if (pk < best) best = pk;
        }
        isOwner = (ownmin == e);
        isWinC  = (best == mypack);
    }

    // heat / inexp at cell (I,J) over this (b,cls) group, candidates only.
    bool heat = false, anyexp = false;
    if (isOwner || isWinC) {
        const float gx = (float)I + 0.5f;
        const float gy = (float)J + 0.5f;
        for (int p = gs; p < ge; ++p) {
            const int m = s_gl[p];
            const float ca = s_ca[m], sa = s_sa[m];
            const float vx =  gx * ca + gy * sa;
            const float vy = -gx * sa + gy * ca;
            const float x3 = s_x3[m], x4 = s_x4[m];
            const float y3 = s_y3[m], y4 = s_y4[m];
            heat   |= (vx >= x3 && vx <= x4 && vy >= y3 && vy <= y4);
            anyexp |= (vx >= x3 - 0.5f && vx <= x4 + 0.5f &&
                       vy >= y3 - 0.5f && vy <= y4 + 0.5f);
        }
    }

    const size_t base = (size_t)b * 8 * 65536 + (size_t)J * 256 + (size_t)I;
    const bool doClear = isOwner && anyexp;
    const bool doWin   = isWinC && heat;

    // ---- hot path (cleared cells, ~9k threads): wave reduce, 1 LDS atomic/wave
    float spz = 0.0f;
    if (doClear) spz = softplusf(predict[base + (size_t)(6 + cls) * 65536]);
    float v0 = (doClear && cls == 0) ? spz : 0.0f;
    float v1 = (doClear && cls == 1) ? spz : 0.0f;
    for (int o = 32; o > 0; o >>= 1) {
        v0 += __shfl_down(v0, o, 64);
        v1 += __shfl_down(v1, o, 64);
    }
    const unsigned long long m0 = __ballot(doClear && cls == 0);
    const unsigned long long m1 = __ballot(doClear && cls == 1);
    if ((t & 63) == 0) {
        if (v0 != 0.0f) atomicAdd(&blksum[14], v0);
        if (v1 != 0.0f) atomicAdd(&blksum[15], v1);
        if (m0) atomicAdd(&blkcnt[2], (unsigned)__popcll(m0));
        if (m1) atomicAdd(&blkcnt[3], (unsigned)__popcll(m1));
    }

    // ---- rare path (winners, ~hundreds total): direct LDS atomics
    if (doWin) {
        const float p0 = predict[base];
        const float p1 = predict[base + 65536];
        const float p2 = predict[base + 2 * 65536];
        const float p3 = predict[base + 3 * 65536];
        const float p4 = predict[base + 4 * 65536];
        const float p5 = predict[base + 5 * 65536];
        const float z  = predict[base + (size_t)(6 + cls) * 65536];
        const float bw = targets[n * 7 + 4] * 0.125f;
        const float bh = targets[n * 7 + 5] * 0.125f;
        const float ang = targets[n * 7 + 6];
        const float xs = sigmoidf(p0) * 5.0f - 2.0f;
        const float ys = sigmoidf(p1) * 5.0f - 2.0f;
        const float pp = sigmoidf(p4) * 2.0f - 1.0f;
        const float qq = sigmoidf(p5) * 2.0f - 1.0f;
        const float tw = logf(bw), th = logf(bh);
        const float wt = th - tw, awt = fabsf(wt);
        float s2a, c2a;
        sincosf(2.0f * ang, &s2a, &c2a);
        atomicAdd(&blksum[0 + cls],  softplusf(-z));
        atomicAdd(&blksum[2 + cls],  (xs - ox) * (xs - ox));
        atomicAdd(&blksum[4 + cls],  (ys - oy) * (ys - oy));
        atomicAdd(&blksum[6 + cls],  (p2 - tw) * (p2 - tw));
        atomicAdd(&blksum[8 + cls],  (p3 - th) * (p3 - th));
        atomicAdd(&blksum[10 + cls], awt * (fabsf(pp - c2a) + fabsf(qq - s2a)));
        atomicAdd(&blksum[12 + cls], awt * fabsf(pp * pp + qq * qq - 1.0f));
        atomicAdd(&blkcnt[cls], 1u);
    }

    __syncthreads();
    // ---- one global atomic per block per nonzero slot (<=20 per block)
    if (t < 16) {
        const float v = blksum[t];
        if (v != 0.0f) atomicAdd(&ws[4 + t], v);
    } else if (t < 20) {
        const unsigned v = blkcnt[t - 16];
        if (v) atomicAdd(&((unsigned*)ws)[t - 16], v);
    }
}

// Full-grid softplus sum over channels 6,7. 524288 float4 total.
// 256 blocks x 256 threads, 8 float4/thread; one partial per block.
__global__ __launch_bounds__(256) void conf_sum(const float* __restrict__ predict,
                                                float* __restrict__ ws) {
    __shared__ float red[4];
    const int t = threadIdx.x;
    const int j = blockIdx.x * 256 + t;      // 0..65535
    const int ch  = 6 + ((j >> 14) & 1);
    const int pos = j & 16383;
    const int bhi = j >> 15;
    float s = 0.0f;
    for (int it = 0; it < 8; ++it) {
        const int b = it * 2 + bhi;
        const float4 v = *reinterpret_cast<const float4*>(
            predict + (size_t)(b * 8 + ch) * 65536 + (size_t)pos * 4);
        s += softplusf(v.x) + softplusf(v.y) + softplusf(v.z) + softplusf(v.w);
    }
    for (int o = 32; o > 0; o >>= 1) s += __shfl_down(s, o, 64);
    if ((t & 63) == 0) red[t >> 6] = s;
    __syncthreads();
    if (t == 0) ws[PART + blockIdx.x] = red[0] + red[1] + red[2] + red[3];
}

__global__ __launch_bounds__(256) void final_kernel(const float* __restrict__ ws,
                                                    float* __restrict__ out) {
    __shared__ float r0[256], r1[256];
    const int t = threadIdx.x;
    const float v = ws[PART + t];
    const int c = (t >> 6) & 1;
    r0[t] = c ? 0.0f : v;
    r1[t] = c ? v : 0.0f;
    __syncthreads();
    for (int o = 128; o > 0; o >>= 1) {
        if (t < o) { r0[t] += r0[t + o]; r1[t] += r1[t + o]; }
        __syncthreads();
    }
    if (t == 0) {
        const unsigned* cnt = (const unsigned*)ws;
        const float sAll[2] = { r0[0], r1[0] };
        float total = 0.0f;
        for (int c2 = 0; c2 < 2; ++c2) {
            const unsigned nobj = cnt[c2];
            if (nobj > 0) {
                const float dn  = (float)nobj;
                const float dno = fmaxf((float)(GSIZE - (int)cnt[2 + c2]), 1.0f);
                total += ws[4 + c2] / dn
                       + (sAll[c2] - ws[18 + c2]) / dno
                       + (ws[6 + c2] + ws[8 + c2] + ws[10 + c2] + ws[12 + c2]
                          + ws[14 + c2] + ws[16 + c2]) / dn;
            }
        }
        out[0] = total;
    }
}

extern "C" void kernel_launch(void* const* d_in, const int* in_sizes, int n_in,
                              void* d_out, int out_size, void* d_ws, size_t ws_size,
                              hipStream_t stream) {
    const float* predict = (const float*)d_in[0];
    const float* targets = (const float*)d_in[1];
    float* out = (float*)d_out;
    float* ws = (float*)d_ws;     // ~14 KB used

    precompute<<<1, 256, 0, stream>>>(targets, ws);
    entry_kernel<<<36, 256, 0, stream>>>(predict, targets, ws);
    conf_sum<<<256, 256, 0, stream>>>(predict, ws);
    final_kernel<<<1, 256, 0, stream>>>(ws, out);
}

// Round 4
// 19.438 us; speedup vs baseline: 28.8851x; 1.5981x over previous
//
#include <hip/hip_runtime.h>
#include <math.h>

// Problem constants (match reference)
#define NTGT 256
#define NB 16
#define NH 256
#define NW 256
#define GSIZE (NB * NH * NW)   // 1,048,576

#define NENTBLK 36             // entry blocks (36*256 = 9216 entries)
#define NCONFBLK 256           // conf blocks
// ---- d_ws layout (4-byte units) ----
// [0..255]    PART: conf partial per conf-block (class = (i>>6)&1)
// [256..975]  ENT:  36 blocks x 20 slots
//             slots: [0..1] conf_obj, [2..3] x, [4..5] y, [6..7] w, [8..9] h,
//                    [10..11] angle, [12..13] ring, [14..15] cleared_softplus,
//                    [16..17] n_obj (as float), [18..19] n_cleared (as float)
#define PART 0
#define ENT  256

__device__ __forceinline__ float softplusf(float z) {
    return fmaxf(z, 0.0f) + log1pf(expf(-fabsf(z)));
}
__device__ __forceinline__ float sigmoidf(float t) {
    return 1.0f / (1.0f + expf(-t));
}

// Fused kernel. Blocks 0..35: entry work (per-block precompute in LDS).
// Blocks 36..291: full-grid softplus partial sums (channels 6,7).
// Every block writes its own ws slots unconditionally -> no init, no
// global atomics, deterministic.
__global__ __launch_bounds__(256) void fused_main(const float* __restrict__ predict,
                                                  const float* __restrict__ targets,
                                                  float* __restrict__ ws) {
#pragma clang fp contract(off)
    const int t = threadIdx.x;

    if (blockIdx.x >= NENTBLK) {
        // ---------------- conf role ----------------
        __shared__ float red[4];
        const int cb = blockIdx.x - NENTBLK;
        const int j = cb * 256 + t;            // 0..65535
        const int ch  = 6 + ((j >> 14) & 1);
        const int pos = j & 16383;
        const int bhi = j >> 15;
        float s = 0.0f;
        for (int it = 0; it < 8; ++it) {
            const int b = it * 2 + bhi;
            const float4 v = *reinterpret_cast<const float4*>(
                predict + (size_t)(b * 8 + ch) * 65536 + (size_t)pos * 4);
            s += softplusf(v.x) + softplusf(v.y) + softplusf(v.z) + softplusf(v.w);
        }
        for (int o = 32; o > 0; o >>= 1) s += __shfl_down(s, o, 64);
        if ((t & 63) == 0) red[t >> 6] = s;
        __syncthreads();
        if (t == 0) ws[PART + cb] = red[0] + red[1] + red[2] + red[3];
        return;
    }

    // ---------------- entry role ----------------
    __shared__ float s_raw[NTGT * 7];
    __shared__ float s_cx[NTGT], s_cy[NTGT], s_ca[NTGT], s_sa[NTGT];
    __shared__ float s_x3[NTGT], s_x4[NTGT], s_y3[NTGT], s_y4[NTGT];
    __shared__ int   s_i0[NTGT], s_j0[NTGT], s_g[NTGT], s_gl[NTGT];
    __shared__ int   s_gs[33];
    __shared__ int   cntg[32];
    __shared__ float blksum[16];
    __shared__ unsigned blkcnt[4];

    for (int i = t; i < NTGT * 7; i += 256) s_raw[i] = targets[i];
    if (t < 32) cntg[t] = 0;
    if (t < 16) blksum[t] = 0.0f;
    if (t >= 16 && t < 20) blkcnt[t - 16] = 0u;
    __syncthreads();

    // per-target precompute (each thread owns target t)
    {
        const float* T = &s_raw[t * 7];
        const int b   = (int)T[0];
        const int cls = (int)T[1];
        const float cx = T[2] * 0.125f, cy = T[3] * 0.125f;
        const float bw = T[4] * 0.125f, bh = T[5] * 0.125f;
        float sa, ca;
        sincosf(T[6], &sa, &ca);
        const float bx =  cx * ca + cy * sa;
        const float by = -cx * sa + cy * ca;
        const int g = b * 2 + cls;
        s_cx[t] = cx;  s_cy[t] = cy;
        s_ca[t] = ca;  s_sa[t] = sa;
        s_x3[t] = bx - bh * 0.5f;  s_x4[t] = bx + bh * 0.5f;
        s_y3[t] = by - bw * 0.5f;  s_y4[t] = by + bw * 0.5f;
        s_i0[t] = (int)floorf(cx - 2.0f);
        s_j0[t] = (int)floorf(cy - 2.0f);
        s_g[t]  = g;
        const int pos = atomicAdd(&cntg[g], 1);
        __syncthreads();
        if (t == 0) {
            int s = 0;
            for (int i = 0; i < 32; ++i) { s_gs[i] = s; s += cntg[i]; }
            s_gs[32] = s;
        }
        __syncthreads();
        s_gl[s_gs[g] + pos] = t;
    }
    __syncthreads();

    const int e = blockIdx.x * 256 + t;     // 0..9215
    const int n = e / 36;
    const int sub = e - n * 36;
    const int kj = sub / 6;
    const int ki = sub - kj * 6;

    const int g = s_g[n];
    const int cls = g & 1;
    const int b = g >> 1;
    const int I = s_i0[n] + ki, J = s_j0[n] + kj;
    const float cx = s_cx[n], cy = s_cy[n];
    const float ox = cx - (float)I;
    const float oy = cy - (float)J;

    const bool validf = (I >= 0 && I < NW && J >= 0 && J < NH) &&
                        (ox >= -2.0f && ox <= 3.0f && oy >= -2.0f && oy <= 3.0f);

    bool isOwner = false, isWinC = false;
    const int gs = s_gs[g], ge = s_gs[g + 1];
    if (validf) {
        const float vfl = fminf(fabsf(ox - 0.5f), fabsf(oy - 0.5f));
        const unsigned long long mypack =
            ((unsigned long long)__float_as_uint(vfl) << 32) | (unsigned)e;
        unsigned long long best = mypack;
        int ownmin = e;
        for (int p = gs; p < ge; ++p) {
            const int m = s_gl[p];
            if (m == n) continue;
            const int kip = I - s_i0[m];
            if (kip < 0 || kip > 5) continue;
            const int kjp = J - s_j0[m];
            if (kjp < 0 || kjp > 5) continue;
            const float oxp = s_cx[m] - (float)I;
            const float oyp = s_cy[m] - (float)J;
            if (!(oxp >= -2.0f && oxp <= 3.0f && oyp >= -2.0f && oyp <= 3.0f)) continue;
            const int ep = (m * 6 + kjp) * 6 + kip;
            ownmin = min(ownmin, ep);
            const float vflp = fminf(fabsf(oxp - 0.5f), fabsf(oyp - 0.5f));
            const unsigned long long pk =
                ((unsigned long long)__float_as_uint(vflp) << 32) | (unsigned)ep;
            if (pk < best) best = pk;
        }
        isOwner = (ownmin == e);
        isWinC  = (best == mypack);
    }

    bool heat = false, anyexp = false;
    if (isOwner || isWinC) {
        const float gx = (float)I + 0.5f;
        const float gy = (float)J + 0.5f;
        for (int p = gs; p < ge; ++p) {
            const int m = s_gl[p];
            const float ca = s_ca[m], sa = s_sa[m];
            const float vx =  gx * ca + gy * sa;
            const float vy = -gx * sa + gy * ca;
            const float x3 = s_x3[m], x4 = s_x4[m];
            const float y3 = s_y3[m], y4 = s_y4[m];
            heat   |= (vx >= x3 && vx <= x4 && vy >= y3 && vy <= y4);
            anyexp |= (vx >= x3 - 0.5f && vx <= x4 + 0.5f &&
                       vy >= y3 - 0.5f && vy <= y4 + 0.5f);
        }
    }

    const size_t base = (size_t)b * 8 * 65536 + (size_t)J * 256 + (size_t)I;
    const bool doClear = isOwner && anyexp;
    const bool doWin   = isWinC && heat;

    // hot path: wave reduce cleared softplus + counts, 1 LDS atomic per wave
    float spz = 0.0f;
    if (doClear) spz = softplusf(predict[base + (size_t)(6 + cls) * 65536]);
    float v0 = (doClear && cls == 0) ? spz : 0.0f;
    float v1 = (doClear && cls == 1) ? spz : 0.0f;
    for (int o = 32; o > 0; o >>= 1) {
        v0 += __shfl_down(v0, o, 64);
        v1 += __shfl_down(v1, o, 64);
    }
    const unsigned long long m0 = __ballot(doClear && cls == 0);
    const unsigned long long m1 = __ballot(doClear && cls == 1);
    if ((t & 63) == 0) {
        if (v0 != 0.0f) atomicAdd(&blksum[14], v0);
        if (v1 != 0.0f) atomicAdd(&blksum[15], v1);
        if (m0) atomicAdd(&blkcnt[2], (unsigned)__popcll(m0));
        if (m1) atomicAdd(&blkcnt[3], (unsigned)__popcll(m1));
    }

    // rare path: winners -> LDS atomics
    if (doWin) {
        const float p0 = predict[base];
        const float p1 = predict[base + 65536];
        const float p2 = predict[base + 2 * 65536];
        const float p3 = predict[base + 3 * 65536];
        const float p4 = predict[base + 4 * 65536];
        const float p5 = predict[base + 5 * 65536];
        const float z  = predict[base + (size_t)(6 + cls) * 65536];
        const float bw = s_raw[n * 7 + 4] * 0.125f;
        const float bh = s_raw[n * 7 + 5] * 0.125f;
        const float ang = s_raw[n * 7 + 6];
        const float xs = sigmoidf(p0) * 5.0f - 2.0f;
        const float ys = sigmoidf(p1) * 5.0f - 2.0f;
        const float pp = sigmoidf(p4) * 2.0f - 1.0f;
        const float qq = sigmoidf(p5) * 2.0f - 1.0f;
        const float tw = logf(bw), th = logf(bh);
        const float wt = th - tw, awt = fabsf(wt);
        float s2a, c2a;
        sincosf(2.0f * ang, &s2a, &c2a);
        atomicAdd(&blksum[0 + cls],  softplusf(-z));
        atomicAdd(&blksum[2 + cls],  (xs - ox) * (xs - ox));
        atomicAdd(&blksum[4 + cls],  (ys - oy) * (ys - oy));
        atomicAdd(&blksum[6 + cls],  (p2 - tw) * (p2 - tw));
        atomicAdd(&blksum[8 + cls],  (p3 - th) * (p3 - th));
        atomicAdd(&blksum[10 + cls], awt * (fabsf(pp - c2a) + fabsf(qq - s2a)));
        atomicAdd(&blksum[12 + cls], awt * fabsf(pp * pp + qq * qq - 1.0f));
        atomicAdd(&blkcnt[cls], 1u);
    }

    __syncthreads();
    // write ALL 20 slots unconditionally (plain stores; no init required)
    if (t < 16) {
        ws[ENT + blockIdx.x * 20 + t] = blksum[t];
    } else if (t < 20) {
        ws[ENT + blockIdx.x * 20 + t] = (float)blkcnt[t - 16];
    }
}

__global__ __launch_bounds__(256) void final_kernel(const float* __restrict__ ws,
                                                    float* __restrict__ out) {
    __shared__ float r0[256], r1[256];
    __shared__ float esum[20];
    const int t = threadIdx.x;
    if (t < 20) esum[t] = 0.0f;
    const float v = ws[PART + t];
    const int c = (t >> 6) & 1;
    r0[t] = c ? 0.0f : v;
    r1[t] = c ? v : 0.0f;
    __syncthreads();
    // entry partials: 36*20 = 720 values
    for (int idx = t; idx < NENTBLK * 20; idx += 256) {
        const int slot = idx % 20;
        atomicAdd(&esum[slot], ws[ENT + idx]);
    }
    for (int o = 128; o > 0; o >>= 1) {
        __syncthreads();
        if (t < o) { r0[t] += r0[t + o]; r1[t] += r1[t + o]; }
    }
    __syncthreads();
    if (t == 0) {
        const float sAll[2] = { r0[0], r1[0] };
        float total = 0.0f;
        for (int c2 = 0; c2 < 2; ++c2) {
            const float nobj = esum[16 + c2];
            if (nobj > 0.0f) {
                const float dn  = nobj;
                const float dno = fmaxf((float)GSIZE - esum[18 + c2], 1.0f);
                total += esum[0 + c2] / dn
                       + (sAll[c2] - esum[14 + c2]) / dno
                       + (esum[2 + c2] + esum[4 + c2] + esum[6 + c2]
                          + esum[8 + c2] + esum[10 + c2] + esum[12 + c2]) / dn;
            }
        }
        out[0] = total;
    }
}

extern "C" void kernel_launch(void* const* d_in, const int* in_sizes, int n_in,
                              void* d_out, int out_size, void* d_ws, size_t ws_size,
                              hipStream_t stream) {
    const float* predict = (const float*)d_in[0];
    const float* targets = (const float*)d_in[1];
    float* out = (float*)d_out;
    float* ws = (float*)d_ws;     // ~4 KB used

    fused_main<<<NENTBLK + NCONFBLK, 256, 0, stream>>>(predict, targets, ws);
    final_kernel<<<1, 256, 0, stream>>>(ws, out);
}